// Round 1
// baseline (586.106 us; speedup 1.0000x reference)
//
#include <hip/hip_runtime.h>
#include <math.h>

// CorrNet fused kernel, fp32 round-1.
// M=128, K=64, T=64, N=131072, D_IN=320.
// 64 samples per block, state in LDS [64][321] (stride%32==1 -> conflict-free),
// lane = sample, wave = column group (weights via wave-uniform s_load).

#define NSAMP 64
#define NTHR  512
#define SSTR  321   // state row stride (floats), 321 % 32 == 1
#define GSTR  65    // gate / zs row stride
#define PSTR  9     // partials row stride

constexpr float INV_SQRT_M = 0.08838834764831845f;   // 1/sqrt(128)
constexpr float INV_SQRT_K = 0.125f;                 // 1/sqrt(64)
constexpr float INV_SQRT_3 = 0.57735026918962576f;
constexpr float TP_NORM    = 0.011048543456039806f;  // 1/sqrt(2*64*64)

// ---------------------------------------------------------------------------
// Init kernel: replicate the numpy trapz that defines C_SILU / C_RELU, in fp64.
// Writes 1/C_SILU to ws[0], 1/C_RELU to ws[1]. Deterministic.
// ---------------------------------------------------------------------------
__global__ void init_consts_kernel(float* __restrict__ ws) {
    __shared__ double red[256];
    const int t = threadIdx.x;
    double acc_s = 0.0, acc_r = 0.0;
    for (int i = t; i <= 20000; i += 256) {
        const double z = -8.0 + (16.0 * (double)i) / 20000.0;
        const double pdf = exp(-0.5 * z * z) / 2.5066282746310002;  // /sqrt(2*pi)
        const double sil = z / (1.0 + exp(-z));
        const double w = (i == 0 || i == 20000) ? 0.5 : 1.0;
        acc_s += w * sil * sil * pdf;
        if (z > 0.0) acc_r += w * z * z * pdf;
    }
    red[t] = acc_s;
    __syncthreads();
    for (int o = 128; o > 0; o >>= 1) {
        if (t < o) red[t] += red[t + o];
        __syncthreads();
    }
    const double tot_s = red[0];
    __syncthreads();
    red[t] = acc_r;
    __syncthreads();
    for (int o = 128; o > 0; o >>= 1) {
        if (t < o) red[t] += red[t + o];
        __syncthreads();
    }
    if (t == 0) {
        const double dz = 16.0 / 20000.0;
        ws[0] = (float)(1.0 / sqrt(tot_s * dz));   // 1/C_SILU
        ws[1] = (float)(1.0 / sqrt(red[0] * dz));  // 1/C_RELU
    }
}

// ---------------------------------------------------------------------------
// One residual block: ys = xs@w0/sqrtM + b0 ; yv = einsum(xv,w1)/sqrtK ;
// xs += silu(ys[:128])/C_SILU ; xv += yv * relu(ys[128:])/C_RELU.
// Sc = this lane's sample row in S; Gc = this lane's gate row.
// r = wave id (0..7): owns 24 ys columns and 24 yv (i,j) units.
// ---------------------------------------------------------------------------
__device__ __forceinline__ void residual_block(
    float* __restrict__ Sc, float* __restrict__ Gc, int r,
    const float* __restrict__ w0, const float* __restrict__ b0,
    const float* __restrict__ w1, float invCS, float invCR)
{
    float sv[24];  // silu contributions (only slots with j < 128 valid)
    float vv[24];  // yv values

    // --- ys: columns j = r*24 .. r*24+23, in 3 sub-blocks of 8 ---
    #pragma unroll
    for (int sb = 0; sb < 3; ++sb) {
        const int j0 = r * 24 + sb * 8;
        float acc[8] = {0.f, 0.f, 0.f, 0.f, 0.f, 0.f, 0.f, 0.f};
        #pragma unroll 4
        for (int m = 0; m < 128; ++m) {
            const float xval = Sc[m];
            const float* wrow = w0 + m * 192 + j0;
            #pragma unroll
            for (int jj = 0; jj < 8; ++jj)
                acc[jj] = fmaf(xval, wrow[jj], acc[jj]);
        }
        #pragma unroll
        for (int jj = 0; jj < 8; ++jj) {
            const int j = j0 + jj;
            const float ys = acc[jj] * INV_SQRT_M + b0[j];
            if (j < 128) {
                const float sig = 1.0f / (1.0f + __expf(-ys));
                sv[sb * 8 + jj] = ys * sig * invCS;
            } else {
                Gc[j - 128] = fmaxf(ys, 0.0f) * invCR;
            }
        }
    }

    // --- yv: units u = r*24 .. (+24);  i = u>>6, j = u&63 ---
    #pragma unroll
    for (int sb = 0; sb < 3; ++sb) {
        const int u0 = r * 24 + sb * 8;
        const int i  = u0 >> 6;
        const int j0 = u0 & 63;
        float acc[8] = {0.f, 0.f, 0.f, 0.f, 0.f, 0.f, 0.f, 0.f};
        #pragma unroll 4
        for (int k = 0; k < 64; ++k) {
            const float xval = Sc[128 + 3 * k + i];
            const float* wrow = w1 + k * 64 + j0;
            #pragma unroll
            for (int jj = 0; jj < 8; ++jj)
                acc[jj] = fmaf(xval, wrow[jj], acc[jj]);
        }
        #pragma unroll
        for (int jj = 0; jj < 8; ++jj)
            vv[sb * 8 + jj] = acc[jj] * INV_SQRT_K;
    }

    __syncthreads();  // all reads of S done; all gate writes to G done

    // --- updates (each (c, feature) written by exactly one thread) ---
    #pragma unroll
    for (int q = 0; q < 24; ++q) {
        const int j = r * 24 + q;
        if (j < 128) Sc[j] += sv[q];
    }
    #pragma unroll
    for (int q = 0; q < 24; ++q) {
        const int u = r * 24 + q;
        const int i = u >> 6;
        const int j = u & 63;
        Sc[128 + 3 * j + i] += vv[q] * Gc[j];
    }
    __syncthreads();
}

// ---------------------------------------------------------------------------
// Main fused kernel: 64 samples per block, 512 threads.
// ---------------------------------------------------------------------------
__global__ __launch_bounds__(NTHR)
void corrnet_fused(const float* __restrict__ x,
                   const float* __restrict__ shift,
                   const float* __restrict__ oscale,
                   const float* __restrict__ w01, const float* __restrict__ b01, const float* __restrict__ w11,
                   const float* __restrict__ w02, const float* __restrict__ b02, const float* __restrict__ w12,
                   const float* __restrict__ w0o, const float* __restrict__ b0o, const float* __restrict__ w1o,
                   const float* __restrict__ wtp0, const float* __restrict__ wtp1,
                   const float* __restrict__ consts,
                   float* __restrict__ out)
{
    __shared__ float S[NSAMP * SSTR];  // per-sample state: f<128 -> xs[f]; f=128+3k+i -> xv[k][i]
    __shared__ float G[NSAMP * GSTR];  // gate g (then reused for zs)
    __shared__ float P[NSAMP * PSTR];  // per-wave partials of the quadratic form

    const int t = threadIdx.x;
    const int c = t & 63;                                    // sample lane
    const int r = __builtin_amdgcn_readfirstlane(t >> 6);    // wave id 0..7 (uniform)
    const long n0 = (long)blockIdx.x * NSAMP;

    const float invCS  = consts[0];
    const float invCR  = consts[1];
    const float inv_os = 1.0f / oscale[0];

    float* Sc = S + c * SSTR;
    float* Gc = G + c * GSTR;

    // ---- load x tile (64 x 320), subtract input_shift ----
    #pragma unroll
    for (int it = 0; it < 10; ++it) {
        const int q  = t + NTHR * it;   // float4 index within tile (64*80 total)
        const int n  = q / 80;
        const int d4 = (q - n * 80) * 4;
        const float4 xv4 = *reinterpret_cast<const float4*>(x + (n0 + n) * 320 + d4);
        const float4 sh4 = *reinterpret_cast<const float4*>(shift + d4);
        float* dst = S + n * SSTR + d4;
        dst[0] = xv4.x - sh4.x;
        dst[1] = xv4.y - sh4.y;
        dst[2] = xv4.z - sh4.z;
        dst[3] = xv4.w - sh4.w;
    }
    __syncthreads();

    residual_block(Sc, Gc, r, w01, b01, w11, invCS, invCR);
    residual_block(Sc, Gc, r, w02, b02, w12, invCS, invCR);

    // ---- zs = xs @ w0_o / sqrtM + b0_o   (columns r*8 .. r*8+7) -> G ----
    {
        const int j0 = r * 8;
        float acc[8] = {0.f, 0.f, 0.f, 0.f, 0.f, 0.f, 0.f, 0.f};
        #pragma unroll 4
        for (int m = 0; m < 128; ++m) {
            const float xval = Sc[m];
            const float* wrow = w0o + m * 64 + j0;
            #pragma unroll
            for (int jj = 0; jj < 8; ++jj)
                acc[jj] = fmaf(xval, wrow[jj], acc[jj]);
        }
        #pragma unroll
        for (int jj = 0; jj < 8; ++jj)
            Gc[j0 + jj] = acc[jj] * INV_SQRT_M + b0o[j0 + jj];
    }

    // ---- zv = einsum(xv, w1_o)/sqrtK  (24 units per wave, in registers) ----
    float zvv[24];
    #pragma unroll
    for (int sb = 0; sb < 3; ++sb) {
        const int u0 = r * 24 + sb * 8;
        const int i  = u0 >> 6;
        const int j0 = u0 & 63;
        float acc[8] = {0.f, 0.f, 0.f, 0.f, 0.f, 0.f, 0.f, 0.f};
        #pragma unroll 4
        for (int k = 0; k < 64; ++k) {
            const float xval = Sc[128 + 3 * k + i];
            const float* wrow = w1o + k * 64 + j0;
            #pragma unroll
            for (int jj = 0; jj < 8; ++jj)
                acc[jj] = fmaf(xval, wrow[jj], acc[jj]);
        }
        #pragma unroll
        for (int jj = 0; jj < 8; ++jj)
            zvv[sb * 8 + jj] = acc[jj] * INV_SQRT_K;
    }
    __syncthreads();             // all reads of S (xv) and writes of G (zs) done

    // store zv into S cols 0..191 (linear u = i*64 + j)
    #pragma unroll
    for (int q = 0; q < 24; ++q)
        Sc[r * 24 + q] = zvv[q];
    __syncthreads();

    // ---- y0 partial: sum_j in [r*8, r*8+8) of (zs @ w_tp0)[j] * zs[j] ----
    float part;
    {
        const int j0 = r * 8;
        float a[8] = {0.f, 0.f, 0.f, 0.f, 0.f, 0.f, 0.f, 0.f};
        #pragma unroll 4
        for (int u = 0; u < 64; ++u) {
            const float zs_u = Gc[u];
            const float* wrow = wtp0 + u * 64 + j0;
            #pragma unroll
            for (int jj = 0; jj < 8; ++jj)
                a[jj] = fmaf(zs_u, wrow[jj], a[jj]);
        }
        float y0p = 0.f;
        #pragma unroll
        for (int jj = 0; jj < 8; ++jj)
            y0p += a[jj] * Gc[j0 + jj];
        part = y0p;
    }

    // ---- y1 partial over this wave's 24 (i, v) units ----
    {
        float y1p = 0.f;
        #pragma unroll
        for (int sb = 0; sb < 3; ++sb) {
            const int u0 = r * 24 + sb * 8;
            const int i  = u0 >> 6;
            const int j0 = u0 & 63;
            float a[8] = {0.f, 0.f, 0.f, 0.f, 0.f, 0.f, 0.f, 0.f};
            #pragma unroll 4
            for (int uu = 0; uu < 64; ++uu) {
                const float zv_u = Sc[(i << 6) + uu];
                const float* wrow = wtp1 + uu * 64 + j0;
                #pragma unroll
                for (int jj = 0; jj < 8; ++jj)
                    a[jj] = fmaf(zv_u, wrow[jj], a[jj]);
            }
            #pragma unroll
            for (int jj = 0; jj < 8; ++jj)
                y1p += a[jj] * Sc[(i << 6) + j0 + jj];
        }
        part += y1p * INV_SQRT_3;
    }

    P[c * PSTR + r] = part;
    __syncthreads();
    if (r == 0) {
        float tot = 0.f;
        #pragma unroll
        for (int q = 0; q < 8; ++q)
            tot += P[c * PSTR + q];
        out[n0 + c] = tot * TP_NORM * inv_os;
    }
}

// ---------------------------------------------------------------------------
extern "C" void kernel_launch(void* const* d_in, const int* in_sizes, int n_in,
                              void* d_out, int out_size, void* d_ws, size_t ws_size,
                              hipStream_t stream) {
    const float* x      = (const float*)d_in[0];
    const float* shift  = (const float*)d_in[1];
    const float* oscale = (const float*)d_in[2];
    const float* w01    = (const float*)d_in[3];
    const float* b01    = (const float*)d_in[4];
    const float* w11    = (const float*)d_in[5];
    const float* w02    = (const float*)d_in[6];
    const float* b02    = (const float*)d_in[7];
    const float* w12    = (const float*)d_in[8];
    const float* w0o    = (const float*)d_in[9];
    const float* b0o    = (const float*)d_in[10];
    const float* w1o    = (const float*)d_in[11];
    const float* wtp0   = (const float*)d_in[12];
    const float* wtp1   = (const float*)d_in[13];
    float* out    = (float*)d_out;
    float* consts = (float*)d_ws;

    init_consts_kernel<<<1, 256, 0, stream>>>(consts);

    const int nblocks = 131072 / NSAMP;  // 2048
    corrnet_fused<<<nblocks, NTHR, 0, stream>>>(
        x, shift, oscale,
        w01, b01, w11, w02, b02, w12,
        w0o, b0o, w1o, wtp0, wtp1, consts, out);
}

// Round 2
// 159.724 us; speedup vs baseline: 3.6695x; 3.6695x over previous
//
#include <hip/hip_runtime.h>
#include <math.h>

// CorrNet fused MFMA-f16 kernel.
// M=128, K=64, T=64, N=131072, D_IN=320.
// Block = 4 waves x 16 samples (wave-private rows -> no __syncthreads).
// State in LDS f16 (A-fragment layout); weights pre-packed f16 B-fragments in d_ws.

typedef _Float16 f16;
typedef _Float16 f16x8 __attribute__((ext_vector_type(8)));
typedef _Float16 f16x4 __attribute__((ext_vector_type(4)));
typedef float    f32x4 __attribute__((ext_vector_type(4)));

#define MFMA16(a, b, c) __builtin_amdgcn_mfma_f32_16x16x32_f16(a, b, c, 0, 0, 0)

constexpr float INV_SQRT_M = 0.08838834764831845f;   // 1/sqrt(128)
constexpr float INV_SQRT_K = 0.125f;                 // 1/sqrt(64)
constexpr float INV_SQRT_3 = 0.57735026918962576f;
constexpr float TP_NORM    = 0.011048543456039806f;  // 1/sqrt(2*64*64)

#define NWAVE 4
#define NTHR  256
#define SX 136   // xs row stride (f16): 272B, quad-stride 17 == 1 mod 8 -> 2-way only
#define SV 72    // xv row stride (f16): 144B, quad-stride 9 == 1 mod 8

// packed-weight segment offsets in f16 units (base = d_ws + 16 bytes)
#define OFF_W01 0
#define OFF_W11 24576
#define OFF_W02 28672
#define OFF_W12 53248
#define OFF_W0O 57344
#define OFF_W1O 65536
#define OFF_TP0 69632
#define OFF_TP1 73728
#define PACK_UNITS 9728   // total f16x8 units

// ---------------------------------------------------------------------------
// consts: replicate numpy trapz for C_SILU / C_RELU in fp64.
// ws[0] = 1/C_SILU, ws[1] = 1/C_RELU.
// ---------------------------------------------------------------------------
__global__ void init_consts_kernel(float* __restrict__ ws) {
    __shared__ double red[256];
    const int t = threadIdx.x;
    double acc_s = 0.0, acc_r = 0.0;
    for (int i = t; i <= 20000; i += 256) {
        const double z = -8.0 + (16.0 * (double)i) / 20000.0;
        const double pdf = exp(-0.5 * z * z) / 2.5066282746310002;
        const double sil = z / (1.0 + exp(-z));
        const double wgt = (i == 0 || i == 20000) ? 0.5 : 1.0;
        acc_s += wgt * sil * sil * pdf;
        if (z > 0.0) acc_r += wgt * z * z * pdf;
    }
    red[t] = acc_s;
    __syncthreads();
    for (int o = 128; o > 0; o >>= 1) { if (t < o) red[t] += red[t + o]; __syncthreads(); }
    const double tot_s = red[0];
    __syncthreads();
    red[t] = acc_r;
    __syncthreads();
    for (int o = 128; o > 0; o >>= 1) { if (t < o) red[t] += red[t + o]; __syncthreads(); }
    if (t == 0) {
        const double dz = 16.0 / 20000.0;
        ws[0] = (float)(1.0 / sqrt(tot_s * dz));
        ws[1] = (float)(1.0 / sqrt(red[0] * dz));
    }
}

// ---------------------------------------------------------------------------
// Pack weights fp32 -> f16 B-fragments.
// Fragment (kstep, nj): lane l, elem e holds W[kstep*32 + (l>>4)*8 + e][nj*16 + (l&15)]
// stored at dst[base + ((kstep*NT + nj)*64 + l)*8 + e].
// ---------------------------------------------------------------------------
__global__ void pack_weights(const float* __restrict__ w01, const float* __restrict__ w11,
                             const float* __restrict__ w02, const float* __restrict__ w12,
                             const float* __restrict__ w0o, const float* __restrict__ w1o,
                             const float* __restrict__ tp0, const float* __restrict__ tp1,
                             f16* __restrict__ dst) {
    int u = blockIdx.x * 256 + threadIdx.x;
    if (u >= PACK_UNITS) return;
    const float* src; int NC, base, lu = u;
    if      (lu < 3072) {            src = w01; NC = 192; base = OFF_W01; }
    else if (lu < 3584) { lu -= 3072; src = w11; NC = 64;  base = OFF_W11; }
    else if (lu < 6656) { lu -= 3584; src = w02; NC = 192; base = OFF_W02; }
    else if (lu < 7168) { lu -= 6656; src = w12; NC = 64;  base = OFF_W12; }
    else if (lu < 8192) { lu -= 7168; src = w0o; NC = 64;  base = OFF_W0O; }
    else if (lu < 8704) { lu -= 8192; src = w1o; NC = 64;  base = OFF_W1O; }
    else if (lu < 9216) { lu -= 8704; src = tp0; NC = 64;  base = OFF_TP0; }
    else                { lu -= 9216; src = tp1; NC = 64;  base = OFF_TP1; }
    const int lane = lu & 63;
    const int frag = lu >> 6;          // kstep*NT + nj
    const int NT = NC >> 4;
    const int kstep = frag / NT, nj = frag - kstep * NT;
    const int row0 = kstep * 32 + (lane >> 4) * 8;
    const int col  = nj * 16 + (lane & 15);
    f16 tmp[8];
    #pragma unroll
    for (int e = 0; e < 8; ++e) tmp[e] = (f16)src[(size_t)(row0 + e) * NC + col];
    *(f16x8*)&dst[(size_t)(base) + (size_t)lu * 8] = *(f16x8*)tmp;
}

// ---------------------------------------------------------------------------
// One residual block, fully wave-private.
// ---------------------------------------------------------------------------
__device__ __forceinline__ void resblock(
    f16 (*__restrict__ lsx)[SX], f16 (*__restrict__ lsv)[16][SV],
    const int lr, const int kb, const int l,
    const f16* __restrict__ w0p, const f16* __restrict__ w1p,
    const float* __restrict__ bg, const float invCS, const float invCR)
{
    f16x8 A1[4];
    #pragma unroll
    for (int ks = 0; ks < 4; ++ks)
        A1[ks] = *(const f16x8*)&lsx[lr][ks * 32 + kb * 8];
    f16x8 AV[3][2];
    #pragma unroll
    for (int i = 0; i < 3; ++i)
        #pragma unroll
        for (int ks = 0; ks < 2; ++ks)
            AV[i][ks] = *(const f16x8*)&lsv[i][lr][ks * 32 + kb * 8];

    float g[4][4];
    // ys GEMM: [16x128]@[128x192], 12 col-tiles
    #pragma unroll
    for (int nj = 0; nj < 12; ++nj) {
        f32x4 acc = {0.f, 0.f, 0.f, 0.f};
        #pragma unroll
        for (int ks = 0; ks < 4; ++ks) {
            f16x8 b = *(const f16x8*)&w0p[(size_t)((ks * 12 + nj) * 64 + l) * 8];
            acc = MFMA16(A1[ks], b, acc);
        }
        const float bias = bg[nj * 16 + lr];
        if (nj < 8) {
            #pragma unroll
            for (int r = 0; r < 4; ++r) {
                const float ys = acc[r] * INV_SQRT_M + bias;
                const float s  = ys / (1.0f + __expf(-ys)) * invCS;
                f16* p = &lsx[kb * 4 + r][nj * 16 + lr];
                *p = (f16)((float)*p + s);
            }
        } else {
            #pragma unroll
            for (int r = 0; r < 4; ++r) {
                const float ys = acc[r] * INV_SQRT_M + bias;
                g[nj - 8][r] = fmaxf(ys, 0.f) * invCR;
            }
        }
    }
    // yv GEMMs: 3 x [16x64]@[64x64], gated update
    #pragma unroll
    for (int i = 0; i < 3; ++i) {
        #pragma unroll
        for (int nj = 0; nj < 4; ++nj) {
            f32x4 acc = {0.f, 0.f, 0.f, 0.f};
            #pragma unroll
            for (int ks = 0; ks < 2; ++ks) {
                f16x8 b = *(const f16x8*)&w1p[(size_t)((ks * 4 + nj) * 64 + l) * 8];
                acc = MFMA16(AV[i][ks], b, acc);
            }
            #pragma unroll
            for (int r = 0; r < 4; ++r) {
                const float yv = acc[r] * INV_SQRT_K;
                f16* p = &lsv[i][kb * 4 + r][nj * 16 + lr];
                *p = (f16)((float)*p + yv * g[nj][r]);
            }
        }
    }
}

// ---------------------------------------------------------------------------
__global__ __launch_bounds__(NTHR, 2)
void corrnet_mfma(const float* __restrict__ x, const float* __restrict__ shift,
                  const float* __restrict__ oscale,
                  const float* __restrict__ b01g, const float* __restrict__ b02g,
                  const float* __restrict__ b0og,
                  const f16* __restrict__ wp, const float* __restrict__ consts,
                  float* __restrict__ out)
{
    __shared__ __align__(16) f16 LSx[NWAVE][16][SX];
    __shared__ __align__(16) f16 LSv[NWAVE][3][16][SV];

    const int t  = threadIdx.x;
    const int l  = t & 63;
    const int w  = __builtin_amdgcn_readfirstlane(t >> 6);
    const int lr = l & 15;
    const int kb = l >> 4;
    const size_t n0 = (size_t)blockIdx.x * (NWAVE * 16) + w * 16;

    const float invCS = consts[0], invCR = consts[1];
    const float inv_os = 1.0f / oscale[0];

    f16 (*lsx)[SX]     = LSx[w];
    f16 (*lsv)[16][SV] = LSv[w];

    // ---- load xs part (features 0..127): 16 rows x 32 float4 ----
    #pragma unroll
    for (int it = 0; it < 8; ++it) {
        const int q   = it * 64 + l;
        const int row = q >> 5;
        const int d4  = (q & 31) * 4;
        const float4 v  = *(const float4*)(x + (n0 + row) * 320 + d4);
        const float4 s4 = *(const float4*)(shift + d4);
        f16 tmp[4] = {(f16)(v.x - s4.x), (f16)(v.y - s4.y),
                      (f16)(v.z - s4.z), (f16)(v.w - s4.w)};
        *(f16x4*)&lsx[row][d4] = *(f16x4*)tmp;
    }
    // ---- load xv part (features 128..319): 16 rows x 48 float4 ----
    #pragma unroll
    for (int it = 0; it < 12; ++it) {
        const int q   = it * 64 + l;
        const int row = q / 48;
        const int c4  = (q - row * 48) * 4;
        const float4 v  = *(const float4*)(x + (n0 + row) * 320 + 128 + c4);
        const float4 s4 = *(const float4*)(shift + 128 + c4);
        const float vals[4] = {v.x - s4.x, v.y - s4.y, v.z - s4.z, v.w - s4.w};
        #pragma unroll
        for (int e = 0; e < 4; ++e) {
            const int g3 = c4 + e;
            lsv[g3 % 3][row][g3 / 3] = (f16)vals[e];
        }
    }

    resblock(lsx, lsv, lr, kb, l, wp + OFF_W01, wp + OFF_W11, b01g, invCS, invCR);
    resblock(lsx, lsv, lr, kb, l, wp + OFF_W02, wp + OFF_W12, b02g, invCS, invCR);

    // ---- output head: zs = xs@w0o + b0o ; zv_i = xv_i@w1o ----
    f16x8 A1[4];
    #pragma unroll
    for (int ks = 0; ks < 4; ++ks)
        A1[ks] = *(const f16x8*)&lsx[lr][ks * 32 + kb * 8];
    f16x8 AV[3][2];
    #pragma unroll
    for (int i = 0; i < 3; ++i)
        #pragma unroll
        for (int ks = 0; ks < 2; ++ks)
            AV[i][ks] = *(const f16x8*)&lsv[i][lr][ks * 32 + kb * 8];

    float zsr[4][4];
    #pragma unroll
    for (int nj = 0; nj < 4; ++nj) {
        f32x4 acc = {0.f, 0.f, 0.f, 0.f};
        #pragma unroll
        for (int ks = 0; ks < 4; ++ks) {
            f16x8 b = *(const f16x8*)&wp[OFF_W0O + (size_t)((ks * 4 + nj) * 64 + l) * 8];
            acc = MFMA16(A1[ks], b, acc);
        }
        const float bias = b0og[nj * 16 + lr];
        #pragma unroll
        for (int r = 0; r < 4; ++r) {
            const float zs = acc[r] * INV_SQRT_M + bias;
            zsr[nj][r] = zs;
            lsx[kb * 4 + r][nj * 16 + lr] = (f16)zs;   // stage for A-reads
        }
    }
    float zvr[3][4][4];
    #pragma unroll
    for (int i = 0; i < 3; ++i) {
        #pragma unroll
        for (int nj = 0; nj < 4; ++nj) {
            f32x4 acc = {0.f, 0.f, 0.f, 0.f};
            #pragma unroll
            for (int ks = 0; ks < 2; ++ks) {
                f16x8 b = *(const f16x8*)&wp[OFF_W1O + (size_t)((ks * 4 + nj) * 64 + l) * 8];
                acc = MFMA16(AV[i][ks], b, acc);
            }
            #pragma unroll
            for (int r = 0; r < 4; ++r) {
                const float zv = acc[r] * INV_SQRT_K;
                zvr[i][nj][r] = zv;
                lsv[i][kb * 4 + r][nj * 16 + lr] = (f16)zv;
            }
        }
    }
    asm volatile("" ::: "memory");  // keep staging writes before re-reads

    // ---- quadratic forms ----
    f16x8 Z[2];
    #pragma unroll
    for (int ks = 0; ks < 2; ++ks)
        Z[ks] = *(const f16x8*)&lsx[lr][ks * 32 + kb * 8];
    f16x8 ZV[3][2];
    #pragma unroll
    for (int i = 0; i < 3; ++i)
        #pragma unroll
        for (int ks = 0; ks < 2; ++ks)
            ZV[i][ks] = *(const f16x8*)&lsv[i][lr][ks * 32 + kb * 8];

    float p[4] = {0.f, 0.f, 0.f, 0.f};
    #pragma unroll
    for (int nj = 0; nj < 4; ++nj) {
        f32x4 acc = {0.f, 0.f, 0.f, 0.f};
        #pragma unroll
        for (int ks = 0; ks < 2; ++ks) {
            f16x8 b = *(const f16x8*)&wp[OFF_TP0 + (size_t)((ks * 4 + nj) * 64 + l) * 8];
            acc = MFMA16(Z[ks], b, acc);
        }
        #pragma unroll
        for (int r = 0; r < 4; ++r) p[r] += acc[r] * zsr[nj][r];
    }
    float p1[4] = {0.f, 0.f, 0.f, 0.f};
    #pragma unroll
    for (int i = 0; i < 3; ++i) {
        #pragma unroll
        for (int nj = 0; nj < 4; ++nj) {
            f32x4 acc = {0.f, 0.f, 0.f, 0.f};
            #pragma unroll
            for (int ks = 0; ks < 2; ++ks) {
                f16x8 b = *(const f16x8*)&wp[OFF_TP1 + (size_t)((ks * 4 + nj) * 64 + l) * 8];
                acc = MFMA16(ZV[i][ks], b, acc);
            }
            #pragma unroll
            for (int r = 0; r < 4; ++r) p1[r] += acc[r] * zvr[i][nj][r];
        }
    }
    #pragma unroll
    for (int r = 0; r < 4; ++r) p[r] += p1[r] * INV_SQRT_3;

    // reduce across the 16 lanes sharing the same rows
    #pragma unroll
    for (int m = 1; m < 16; m <<= 1)
        #pragma unroll
        for (int r = 0; r < 4; ++r) p[r] += __shfl_xor(p[r], m, 64);

    if (lr == 0) {
        #pragma unroll
        for (int r = 0; r < 4; ++r)
            out[n0 + kb * 4 + r] = p[r] * TP_NORM * inv_os;
    }
}

// ---------------------------------------------------------------------------
extern "C" void kernel_launch(void* const* d_in, const int* in_sizes, int n_in,
                              void* d_out, int out_size, void* d_ws, size_t ws_size,
                              hipStream_t stream) {
    const float* x      = (const float*)d_in[0];
    const float* shift  = (const float*)d_in[1];
    const float* oscale = (const float*)d_in[2];
    const float* w01    = (const float*)d_in[3];
    const float* b01    = (const float*)d_in[4];
    const float* w11    = (const float*)d_in[5];
    const float* w02    = (const float*)d_in[6];
    const float* b02    = (const float*)d_in[7];
    const float* w12    = (const float*)d_in[8];
    const float* w0o    = (const float*)d_in[9];
    const float* b0o    = (const float*)d_in[10];
    const float* w1o    = (const float*)d_in[11];
    const float* wtp0   = (const float*)d_in[12];
    const float* wtp1   = (const float*)d_in[13];
    float* out    = (float*)d_out;
    float* consts = (float*)d_ws;
    f16*   wp     = (f16*)((char*)d_ws + 16);

    init_consts_kernel<<<1, 256, 0, stream>>>(consts);
    pack_weights<<<(PACK_UNITS + 255) / 256, 256, 0, stream>>>(
        w01, w11, w02, w12, w0o, w1o, wtp0, wtp1, wp);

    const int nblocks = 131072 / (NWAVE * 16);  // 2048
    corrnet_mfma<<<nblocks, NTHR, 0, stream>>>(
        x, shift, oscale, b01, b02, b0o, wp, consts, out);
}